// Round 9
// baseline (287.447 us; speedup 1.0000x reference)
//
#include <hip/hip_runtime.h>

typedef unsigned short u16;
typedef __bf16 bf16x8 __attribute__((ext_vector_type(8)));
typedef float f32x4 __attribute__((ext_vector_type(4)));

#define D_MODEL 1024
#define S_LEN 2048
#define NH 16
#define DK 64
#define BATCH 2
#define M_ROWS (BATCH * S_LEN) /* 4096 */
#define NQKV (3 * D_MODEL)     /* 3072 */

__device__ __forceinline__ u16 f2bf(float x) {
  union { __bf16 h; u16 u; } v; v.h = (__bf16)x;  // native cast -> v_cvt_pk_bf16_f32
  return v.u;
}
__device__ __forceinline__ float bf2f(u16 b) {
  union { unsigned u; float f; } v; v.u = ((unsigned)b) << 16; return v.f;
}
__device__ __forceinline__ void gload16(const void* g, void* l) {
  __builtin_amdgcn_global_load_lds((const __attribute__((address_space(1))) unsigned int*)g,
                                   (__attribute__((address_space(3))) unsigned int*)l, 16, 0, 0);
}

// ---------------- pack f32 -> bf16 (coalesced, 8 elems/thread) ----------------
__global__ __launch_bounds__(256) void pack_bf16(const float* __restrict__ in, u16* __restrict__ out) {
  const int idx = (blockIdx.x * 256 + threadIdx.x) * 8;
  float4 a = *(const float4*)&in[idx];
  float4 b = *(const float4*)&in[idx + 4];
  unsigned p0 = (unsigned)f2bf(a.x) | ((unsigned)f2bf(a.y) << 16);
  unsigned p1 = (unsigned)f2bf(a.z) | ((unsigned)f2bf(a.w) << 16);
  unsigned p2 = (unsigned)f2bf(b.x) | ((unsigned)f2bf(b.y) << 16);
  unsigned p3 = (unsigned)f2bf(b.z) | ((unsigned)f2bf(b.w) << 16);
  int4 o; o.x = (int)p0; o.y = (int)p1; o.z = (int)p2; o.w = (int)p3;
  *(int4*)&out[idx] = o;
}

// -------- tiled transpose + pack: in f32 [R,C] -> out bf16 [C,R] --------
__global__ __launch_bounds__(256) void transpose_pack(const float* __restrict__ in, u16* __restrict__ out,
                                                      int R, int C) {
  __shared__ u16 T[64][68];
  const int r0 = blockIdx.x * 64, c0 = blockIdx.y * 64;
  const int t = threadIdx.x;
  const int col = t & 63, rq = t >> 6;
#pragma unroll
  for (int s = 0; s < 16; ++s) {
    int row = s * 4 + rq;
    T[col][row] = f2bf(in[(size_t)(r0 + row) * C + c0 + col]);
  }
  __syncthreads();
#pragma unroll
  for (int s = 0; s < 16; ++s) {
    int crow = s * 4 + rq;
    out[(size_t)(c0 + crow) * R + r0 + col] = T[crow][col];
  }
}

// -------- bf16 GEMM: C[M,N] = A[M,K]*BT[N,K]^T + bias; 128x128, BK=64 --------
template <int OUTF32>
__global__ __launch_bounds__(256) void gemm_bt(const u16* __restrict__ A, const u16* __restrict__ BT,
                                               const float* __restrict__ bias, void* __restrict__ outp,
                                               int K, int N) {
  __shared__ u16 As[2][128 * 64];
  __shared__ u16 Bs[2][128 * 64];
  const int m0 = blockIdx.x * 128, n0 = blockIdx.y * 128;
  const int t = threadIdx.x, lane = t & 63, w = t >> 6;
  const int wr = w >> 1, wc = w & 1;
  const int l15 = lane & 15, l4 = lane >> 4;
  const int srow = lane >> 3, schunk = lane & 7;

  f32x4 acc[4][4] = {};

#define STAGE_G(buf, k0)                                                        \
  do {                                                                          \
    _Pragma("unroll") for (int i = 0; i < 4; ++i) {                             \
      int r0 = (i * 4 + w) * 8;                                                 \
      int r = r0 + srow;                                                        \
      int sc = (schunk ^ (r & 7)) * 8;                                          \
      gload16(&A[(size_t)(m0 + r) * K + (k0) + sc], &As[buf][r0 * 64]);         \
      gload16(&BT[(size_t)(n0 + r) * K + (k0) + sc], &Bs[buf][r0 * 64]);        \
    }                                                                           \
  } while (0)

  STAGE_G(0, 0);
  __syncthreads();
  const int nk = K / 64;
  int cur = 0;
  for (int t0 = 0; t0 < nk; ++t0) {
    if (t0 + 1 < nk) STAGE_G(cur ^ 1, (t0 + 1) * 64);
#pragma unroll
    for (int ks = 0; ks < 2; ++ks) {
      bf16x8 af[4], bfr[4];
#pragma unroll
      for (int g = 0; g < 4; ++g) {
        int ra = wr * 64 + g * 16 + l15;
        int rb = wc * 64 + g * 16 + l15;
        af[g]  = *(const bf16x8*)&As[cur][ra * 64 + ((ks * 4 + l4) ^ (ra & 7)) * 8];
        bfr[g] = *(const bf16x8*)&Bs[cur][rb * 64 + ((ks * 4 + l4) ^ (rb & 7)) * 8];
      }
#pragma unroll
      for (int mg = 0; mg < 4; ++mg)
#pragma unroll
        for (int ng = 0; ng < 4; ++ng)
          acc[mg][ng] = __builtin_amdgcn_mfma_f32_16x16x32_bf16(af[mg], bfr[ng], acc[mg][ng], 0, 0, 0);
    }
    __syncthreads();
    cur ^= 1;
  }
#undef STAGE_G
  const int rowb = m0 + wr * 64, colb = n0 + wc * 64;
#pragma unroll
  for (int mg = 0; mg < 4; ++mg)
#pragma unroll
    for (int ng = 0; ng < 4; ++ng) {
      int col = colb + ng * 16 + l15;
      float bv = bias[col];
#pragma unroll
      for (int j = 0; j < 4; ++j) {
        int row = rowb + mg * 16 + l4 * 4 + j;
        float val = acc[mg][ng][j] + bv;
        if (OUTF32) ((float*)outp)[(size_t)row * N + col] = val;
        else        ((u16*)outp)[(size_t)row * N + col] = f2bf(val);
      }
    }
}

// -------- fused attention (k-split waves for occupancy) --------
// grid = B*NH*32 blocks (64 q-rows each), 8 waves (512 thr) = 4 q-groups x 2
// k-groups; each wave: 16 q-rows x 32 k-cols. LDS ~43.5KB -> 3 blocks/CU
// (24 waves/CU vs R3's 16). Mask read from global (L1-resident). Cross-kg
// rowsum exchange after pass 1; cross-kg O reduction at the end.
__global__ __launch_bounds__(512, 6) void attn_fused(const u16* __restrict__ qkv, const float* __restrict__ mask,
                                                     float* __restrict__ scores, u16* __restrict__ attnout) {
  __shared__ u16 Ks[2][64 * 64];
  __shared__ u16 Vt[2][64 * 68];   // V^T, pad 68
  __shared__ u16 Ps[8][16][40];    // per-wave bf16 P tile (16 rows x 32 k-cols)
  __shared__ float RS[4][16][2];   // per-qg rowsum halves
  const int bid = blockIdx.x;
  const int qt = bid & 31, h = (bid >> 5) & 15, b = bid >> 9;
  const int t = threadIdx.x, lane = t & 63, w = t >> 6;
  const int qg = w >> 1, kg = w & 1;
  const int l15 = lane & 15, l4 = lane >> 4;
  const u16* kbase = qkv + (size_t)b * S_LEN * NQKV + D_MODEL + h * DK;
  const u16* vbase = kbase + D_MODEL;
  const float* mrow = mask + b * S_LEN;

  // Q fragments (16 rows per wave), pre-scaled by 1/8 (exact in bf16)
  bf16x8 qf[2];
  {
    const int qrow = qt * 64 + qg * 16 + l15;
    const u16* qp = qkv + (size_t)(b * S_LEN + qrow) * NQKV + h * DK;
#pragma unroll
    for (int ks = 0; ks < 2; ++ks) {
      union { bf16x8 v; u16 s[8]; } qa;
      qa.v = *(const bf16x8*)&qp[ks * 32 + l4 * 8];
#pragma unroll
      for (int e = 0; e < 8; ++e) qa.s[e] = f2bf(bf2f(qa.s[e]) * 0.125f);
      qf[ks] = qa.v;
    }
  }

  const int krow = t >> 3;                       // 0..63 (one 16B chunk/thread)
  const int kchunk = ((t & 7) ^ (krow & 7)) * 8; // pre-swizzled source
#define STAGE_K(buf, kt) \
  gload16(&kbase[(size_t)((kt) * 64 + krow) * NQKV + kchunk], &Ks[buf][w * 512])

  float ps4[4] = {0.f, 0.f, 0.f, 0.f};
  int cur = 0;
  // ---- pass 1: partial row sums over this wave's k-half ----
  STAGE_K(0, 0);
  __syncthreads();
  for (int kt = 0; kt < 32; ++kt) {
    if (kt + 1 < 32) STAGE_K(cur ^ 1, kt + 1);
    f32x4 sacc[2] = {};
#pragma unroll
    for (int ks = 0; ks < 2; ++ks) {
      bf16x8 kf[2];
#pragma unroll
      for (int n = 0; n < 2; ++n) {
        int kr = kg * 32 + n * 16 + l15;
        kf[n] = *(const bf16x8*)&Ks[cur][kr * 64 + ((ks * 4 + l4) ^ (kr & 7)) * 8];
      }
#pragma unroll
      for (int n = 0; n < 2; ++n)
        sacc[n] = __builtin_amdgcn_mfma_f32_16x16x32_bf16(qf[ks], kf[n], sacc[n], 0, 0, 0);
    }
#pragma unroll
    for (int n = 0; n < 2; ++n) {
      float m = mrow[kt * 64 + kg * 32 + n * 16 + l15];
      float mb = -10000.0f * (1.0f - m);
#pragma unroll
      for (int j = 0; j < 4; ++j) ps4[j] += __expf(sacc[n][j] + mb);
    }
    __syncthreads();
    cur ^= 1;
  }
#pragma unroll
  for (int off = 1; off < 16; off <<= 1)
#pragma unroll
    for (int j = 0; j < 4; ++j) ps4[j] += __shfl_xor(ps4[j], off, 64);
  if (l15 == 0)
#pragma unroll
    for (int j = 0; j < 4; ++j) RS[qg][l4 * 4 + j][kg] = ps4[j];
  __syncthreads();
  float inv4[4];
#pragma unroll
  for (int j = 0; j < 4; ++j) inv4[j] = 1.0f / (RS[qg][l4 * 4 + j][0] + RS[qg][l4 * 4 + j][1]);

  // ---- pass 2 ----
  f32x4 oacc[4] = {};
  const int vr = t >> 3, vc = (t & 7) * 8;
  const size_t sbase = ((size_t)((b * NH + h) * S_LEN + qt * 64 + qg * 16 + l4 * 4)) * S_LEN + l15;

  STAGE_K(0, 0);  // cur == 0 here
  {
    const u16* vp = &vbase[(size_t)vr * NQKV + vc];
    int4 va0 = *(const int4*)vp;
    const u16* s0 = (const u16*)&va0;
#pragma unroll
    for (int i = 0; i < 8; ++i) Vt[0][(vc + i) * 68 + vr] = s0[i];
  }
  __syncthreads();
  cur = 0;
  for (int kt = 0; kt < 32; ++kt) {
    const bool hn = (kt + 1 < 32);
    int4 va;
    if (hn) {
      STAGE_K(cur ^ 1, kt + 1);
      va = *(const int4*)&vbase[(size_t)((kt + 1) * 64 + vr) * NQKV + vc];
    }
    f32x4 sacc[2] = {};
#pragma unroll
    for (int ks = 0; ks < 2; ++ks) {
      bf16x8 kf[2];
#pragma unroll
      for (int n = 0; n < 2; ++n) {
        int kr = kg * 32 + n * 16 + l15;
        kf[n] = *(const bf16x8*)&Ks[cur][kr * 64 + ((ks * 4 + l4) ^ (kr & 7)) * 8];
      }
#pragma unroll
      for (int n = 0; n < 2; ++n)
        sacc[n] = __builtin_amdgcn_mfma_f32_16x16x32_bf16(qf[ks], kf[n], sacc[n], 0, 0, 0);
    }
    // exp -> direct f32 scores stores + bf16 P into per-wave LDS tile
#pragma unroll
    for (int n = 0; n < 2; ++n) {
      float m = mrow[kt * 64 + kg * 32 + n * 16 + l15];
      float mb = -10000.0f * (1.0f - m);
#pragma unroll
      for (int j = 0; j < 4; ++j) {
        float p = __expf(sacc[n][j] + mb) * inv4[j];
        scores[sbase + (size_t)j * S_LEN + kt * 64 + kg * 32 + n * 16] = p;
        Ps[w][l4 * 4 + j][n * 16 + l15] = f2bf(p);
      }
    }
    // PV over this wave's 32-k half (Ps wave-private; Vt[cur] staged last iter)
    {
      bf16x8 pa = *(const bf16x8*)&Ps[w][l15][l4 * 8];
      bf16x8 vf[4];
#pragma unroll
      for (int dn = 0; dn < 4; ++dn)
        vf[dn] = *(const bf16x8*)&Vt[cur][(dn * 16 + l15) * 68 + kg * 32 + l4 * 8];
#pragma unroll
      for (int dn = 0; dn < 4; ++dn)
        oacc[dn] = __builtin_amdgcn_mfma_f32_16x16x32_bf16(pa, vf[dn], oacc[dn], 0, 0, 0);
    }
    if (hn) {  // write next V tile (buffer read last iter; all waves past that barrier)
      const u16* s0 = (const u16*)&va;
#pragma unroll
      for (int i = 0; i < 8; ++i) Vt[cur ^ 1][(vc + i) * 68 + vr] = s0[i];
    }
    __syncthreads();
    cur ^= 1;
  }
#undef STAGE_K
  // cross-kg O reduction (reuse Ks region as f32 scratch), then write O (bf16)
  float* OX = (float*)&Ks[0][0];  // 16 rows*4 qg x 64 cols f32 = 16 KB
  if (kg == 1) {
#pragma unroll
    for (int dn = 0; dn < 4; ++dn)
#pragma unroll
      for (int j = 0; j < 4; ++j)
        OX[(qg * 16 + l4 * 4 + j) * 64 + dn * 16 + l15] = oacc[dn][j];
  }
  __syncthreads();
  if (kg == 0) {
#pragma unroll
    for (int dn = 0; dn < 4; ++dn) {
      int col = h * DK + dn * 16 + l15;
#pragma unroll
      for (int j = 0; j < 4; ++j) {
        int row = b * S_LEN + qt * 64 + qg * 16 + l4 * 4 + j;
        float o = oacc[dn][j] + OX[(qg * 16 + l4 * 4 + j) * 64 + dn * 16 + l15];
        attnout[(size_t)row * D_MODEL + col] = f2bf(o);
      }
    }
  }
}

extern "C" void kernel_launch(void* const* d_in, const int* in_sizes, int n_in,
                              void* d_out, int out_size, void* d_ws, size_t ws_size,
                              hipStream_t stream) {
  const float* x      = (const float*)d_in[0];
  const float* mask   = (const float*)d_in[1];
  const float* W_attn = (const float*)d_in[2];
  const float* b_attn = (const float*)d_in[3];
  const float* W_proj = (const float*)d_in[4];
  const float* b_proj = (const float*)d_in[5];
  float* out    = (float*)d_out;
  float* scores = out + (size_t)M_ROWS * D_MODEL;

  char* ws = (char*)d_ws;
  u16* xb     = (u16*)ws;                          // 8 MB  : x bf16 [4096,1024]
  u16* wqkvT  = (u16*)(ws + (size_t)(8  << 20));   // 6 MB  : W_attn^T bf16 [3072,1024]
  u16* wprojT = (u16*)(ws + (size_t)(14 << 20));   // 2 MB  : W_proj^T bf16 [1024,1024]
  u16* qkv    = (u16*)(ws + (size_t)(16 << 20));   // 24 MB : qkv bf16 [4096,3072]
  u16* attnb  = (u16*)(ws + (size_t)(40 << 20));   // 8 MB  : attn out bf16 [4096,1024]

  pack_bf16<<<(M_ROWS * D_MODEL) / (256 * 8), 256, 0, stream>>>(x, xb);
  transpose_pack<<<dim3(D_MODEL / 64, NQKV / 64), 256, 0, stream>>>(W_attn, wqkvT, D_MODEL, NQKV);
  transpose_pack<<<dim3(D_MODEL / 64, D_MODEL / 64), 256, 0, stream>>>(W_proj, wprojT, D_MODEL, D_MODEL);
  gemm_bt<0><<<dim3(M_ROWS / 128, NQKV / 128), 256, 0, stream>>>(xb, wqkvT, b_attn, (void*)qkv, D_MODEL, NQKV);
  attn_fused<<<BATCH * NH * (S_LEN / 64), 512, 0, stream>>>(qkv, mask, scores, attnb);
  gemm_bt<1><<<dim3(M_ROWS / 128, D_MODEL / 128), 256, 0, stream>>>(attnb, wprojT, b_proj, (void*)out, D_MODEL, D_MODEL);
}

// Round 10
// 241.092 us; speedup vs baseline: 1.1923x; 1.1923x over previous
//
#include <hip/hip_runtime.h>

typedef unsigned short u16;
typedef __bf16 bf16x8 __attribute__((ext_vector_type(8)));
typedef float f32x4 __attribute__((ext_vector_type(4)));

#define D_MODEL 1024
#define S_LEN 2048
#define NH 16
#define DK 64
#define BATCH 2
#define M_ROWS (BATCH * S_LEN) /* 4096 */
#define NQKV (3 * D_MODEL)     /* 3072 */

__device__ __forceinline__ u16 f2bf(float x) {
  union { __bf16 h; u16 u; } v; v.h = (__bf16)x;
  return v.u;
}
__device__ __forceinline__ float bf2f(u16 b) {
  union { unsigned u; float f; } v; v.u = ((unsigned)b) << 16; return v.f;
}
__device__ __forceinline__ void gload16(const void* g, void* l) {
  __builtin_amdgcn_global_load_lds((const __attribute__((address_space(1))) unsigned int*)g,
                                   (__attribute__((address_space(3))) unsigned int*)l, 16, 0, 0);
}

// ---------------- pack f32 -> bf16 ----------------
__global__ __launch_bounds__(256) void pack_bf16(const float* __restrict__ in, u16* __restrict__ out) {
  const int idx = (blockIdx.x * 256 + threadIdx.x) * 8;
  float4 a = *(const float4*)&in[idx];
  float4 b = *(const float4*)&in[idx + 4];
  unsigned p0 = (unsigned)f2bf(a.x) | ((unsigned)f2bf(a.y) << 16);
  unsigned p1 = (unsigned)f2bf(a.z) | ((unsigned)f2bf(a.w) << 16);
  unsigned p2 = (unsigned)f2bf(b.x) | ((unsigned)f2bf(b.y) << 16);
  unsigned p3 = (unsigned)f2bf(b.z) | ((unsigned)f2bf(b.w) << 16);
  int4 o; o.x = (int)p0; o.y = (int)p1; o.z = (int)p2; o.w = (int)p3;
  *(int4*)&out[idx] = o;
}

// -------- tiled transpose + pack --------
__global__ __launch_bounds__(256) void transpose_pack(const float* __restrict__ in, u16* __restrict__ out,
                                                      int R, int C) {
  __shared__ u16 T[64][68];
  const int r0 = blockIdx.x * 64, c0 = blockIdx.y * 64;
  const int t = threadIdx.x;
  const int col = t & 63, rq = t >> 6;
#pragma unroll
  for (int s = 0; s < 16; ++s) {
    int row = s * 4 + rq;
    T[col][row] = f2bf(in[(size_t)(r0 + row) * C + c0 + col]);
  }
  __syncthreads();
#pragma unroll
  for (int s = 0; s < 16; ++s) {
    int crow = s * 4 + rq;
    out[(size_t)(c0 + crow) * R + r0 + col] = T[crow][col];
  }
}

// -------- 2-phase 128x128 bf16 GEMM (proven; used for proj) --------
template <int OUTF32>
__global__ __launch_bounds__(256) void gemm_bt(const u16* __restrict__ A, const u16* __restrict__ BT,
                                               const float* __restrict__ bias, void* __restrict__ outp,
                                               int K, int N) {
  __shared__ u16 As[2][128 * 64];
  __shared__ u16 Bs[2][128 * 64];
  const int m0 = blockIdx.x * 128, n0 = blockIdx.y * 128;
  const int t = threadIdx.x, lane = t & 63, w = t >> 6;
  const int wr = w >> 1, wc = w & 1;
  const int l15 = lane & 15, l4 = lane >> 4;
  const int srow = lane >> 3, schunk = lane & 7;

  f32x4 acc[4][4] = {};

#define STAGE_G(buf, k0)                                                        \
  do {                                                                          \
    _Pragma("unroll") for (int i = 0; i < 4; ++i) {                             \
      int r0 = (i * 4 + w) * 8;                                                 \
      int r = r0 + srow;                                                        \
      int sc = (schunk ^ (r & 7)) * 8;                                          \
      gload16(&A[(size_t)(m0 + r) * K + (k0) + sc], &As[buf][r0 * 64]);         \
      gload16(&BT[(size_t)(n0 + r) * K + (k0) + sc], &Bs[buf][r0 * 64]);        \
    }                                                                           \
  } while (0)

  STAGE_G(0, 0);
  __syncthreads();
  const int nk = K / 64;
  int cur = 0;
  for (int t0 = 0; t0 < nk; ++t0) {
    if (t0 + 1 < nk) STAGE_G(cur ^ 1, (t0 + 1) * 64);
#pragma unroll
    for (int ks = 0; ks < 2; ++ks) {
      bf16x8 af[4], bfr[4];
#pragma unroll
      for (int g = 0; g < 4; ++g) {
        int ra = wr * 64 + g * 16 + l15;
        int rb = wc * 64 + g * 16 + l15;
        af[g]  = *(const bf16x8*)&As[cur][ra * 64 + ((ks * 4 + l4) ^ (ra & 7)) * 8];
        bfr[g] = *(const bf16x8*)&Bs[cur][rb * 64 + ((ks * 4 + l4) ^ (rb & 7)) * 8];
      }
#pragma unroll
      for (int mg = 0; mg < 4; ++mg)
#pragma unroll
        for (int ng = 0; ng < 4; ++ng)
          acc[mg][ng] = __builtin_amdgcn_mfma_f32_16x16x32_bf16(af[mg], bfr[ng], acc[mg][ng], 0, 0, 0);
    }
    __syncthreads();
    cur ^= 1;
  }
#undef STAGE_G
  const int rowb = m0 + wr * 64, colb = n0 + wc * 64;
#pragma unroll
  for (int mg = 0; mg < 4; ++mg)
#pragma unroll
    for (int ng = 0; ng < 4; ++ng) {
      int col = colb + ng * 16 + l15;
      float bv = bias[col];
#pragma unroll
      for (int j = 0; j < 4; ++j) {
        int row = rowb + mg * 16 + l4 * 4 + j;
        float val = acc[mg][ng][j] + bv;
        if (OUTF32) ((float*)outp)[(size_t)row * N + col] = val;
        else        ((u16*)outp)[(size_t)row * N + col] = f2bf(val);
      }
    }
}

// -------- 8-phase 256x256 bf16 GEMM (m201 template port; used for QKV) --------
// 8 waves (2M x 4N), per-wave 128x64 output. LDS 128KB: [buf][half][128*64] for
// A and B. st_16x32 swizzle: elem col ^= ((row>>2)&1)<<4, applied on the
// pre-swizzled gload source AND on ds_read (both-sides rule). Per K-tile: 4
// phases {ds_read, 1 half-tile stage, barrier, lgkm0, prio1, 16 MFMA, prio0,
// barrier}. Stage slots (tile t, buf c): P1:T+1.b1, P2:T+1.a0, P3:T+1.a1,
// P4:T+2.b0 -> each targets a region fully consumed >=1 barrier earlier.
// vmcnt(2) at P4 retires exactly T+1 (leaves T+2.b0 in flight); never 0 in loop.
template <int OUTF32>
__global__ __launch_bounds__(512, 2) void gemm8p(const u16* __restrict__ A, const u16* __restrict__ BT,
                                                 const float* __restrict__ bias, void* __restrict__ outp,
                                                 int K, int N) {
  __shared__ u16 As[2][2][128 * 64];
  __shared__ u16 Bs[2][2][128 * 64];
  const int m0 = blockIdx.x * 256, n0 = blockIdx.y * 256;
  const int t = threadIdx.x, lane = t & 63, w = t >> 6;
  const int wm = w >> 2, wn = w & 3;
  const int l15 = lane & 15, l4 = lane >> 4;
  const int flip = ((l15 >> 2) & 1) << 4;  // read-side swizzle (row bit2 = l15 bit2)

  const u16* Ab[2] = { A + (size_t)m0 * K, A + (size_t)(m0 + 128) * K };
  const u16* Bb[2] = { BT + (size_t)n0 * K, BT + (size_t)(n0 + 128) * K };

  // stage one 128x64 half-tile: 2 gload16/thread; linear LDS dest, source col
  // pre-XORed so content at linear (r,c) is logical col c^((r>>2&1)<<4).
#define STG(dst, src, kt)                                                       \
  do {                                                                          \
    _Pragma("unroll") for (int i = 0; i < 2; ++i) {                             \
      int r = i * 64 + w * 8 + (lane >> 3);                                     \
      int sc = ((lane & 7) * 8) ^ (((r >> 2) & 1) << 4);                        \
      gload16(&(src)[(size_t)r * K + (size_t)(kt) * 64 + sc],                   \
              &(dst)[i * 4096 + w * 512]);                                      \
    }                                                                           \
  } while (0)

  f32x4 acc[8][4] = {};
  // prologue: T0 all halves + T1.b0 ; vmcnt(2) retires T0, leaves T1.b0
  STG(As[0][0], Ab[0], 0); STG(As[0][1], Ab[1], 0);
  STG(Bs[0][0], Bb[0], 0); STG(Bs[0][1], Bb[1], 0);
  STG(Bs[1][0], Bb[0], 1);
  asm volatile("s_waitcnt vmcnt(2)" ::: "memory");
  __builtin_amdgcn_s_barrier();

  const int nk = K >> 6;
  const int rlb = (wn & 1) * 64;  // B local row base within half
  for (int kt = 0; kt < nk; ++kt) {
    const int c = kt & 1;
    bf16x8 af[4], bfr[4];
    // ---- P1: kh0, m0-3 x n0-3 ----
#pragma unroll
    for (int mr = 0; mr < 4; ++mr)
      af[mr] = *(const bf16x8*)&As[c][wm][(mr * 16 + l15) * 64 + ((l4 * 8) ^ flip)];
#pragma unroll
    for (int nr = 0; nr < 4; ++nr)
      bfr[nr] = *(const bf16x8*)&Bs[c][wn >> 1][(rlb + nr * 16 + l15) * 64 + ((l4 * 8) ^ flip)];
    if (kt + 1 < nk) STG(Bs[c ^ 1][1], Bb[1], kt + 1);
    __builtin_amdgcn_s_barrier();
    asm volatile("s_waitcnt lgkmcnt(0)" ::: "memory");
    __builtin_amdgcn_s_setprio(1);
#pragma unroll
    for (int mr = 0; mr < 4; ++mr)
#pragma unroll
      for (int nr = 0; nr < 4; ++nr)
        acc[mr][nr] = __builtin_amdgcn_mfma_f32_16x16x32_bf16(af[mr], bfr[nr], acc[mr][nr], 0, 0, 0);
    __builtin_amdgcn_s_setprio(0);
    __builtin_amdgcn_s_barrier();
    // ---- P2: kh0, m4-7 x n0-3 (B frags held in regs) ----
#pragma unroll
    for (int mr = 0; mr < 4; ++mr)
      af[mr] = *(const bf16x8*)&As[c][wm][((4 + mr) * 16 + l15) * 64 + ((l4 * 8) ^ flip)];
    if (kt + 1 < nk) STG(As[c ^ 1][0], Ab[0], kt + 1);
    __builtin_amdgcn_s_barrier();
    asm volatile("s_waitcnt lgkmcnt(0)" ::: "memory");
    __builtin_amdgcn_s_setprio(1);
#pragma unroll
    for (int mr = 0; mr < 4; ++mr)
#pragma unroll
      for (int nr = 0; nr < 4; ++nr)
        acc[4 + mr][nr] = __builtin_amdgcn_mfma_f32_16x16x32_bf16(af[mr], bfr[nr], acc[4 + mr][nr], 0, 0, 0);
    __builtin_amdgcn_s_setprio(0);
    __builtin_amdgcn_s_barrier();
    // ---- P3: kh1, m0-3 x n0-3 ----
#pragma unroll
    for (int mr = 0; mr < 4; ++mr)
      af[mr] = *(const bf16x8*)&As[c][wm][(mr * 16 + l15) * 64 + ((32 + l4 * 8) ^ flip)];
#pragma unroll
    for (int nr = 0; nr < 4; ++nr)
      bfr[nr] = *(const bf16x8*)&Bs[c][wn >> 1][(rlb + nr * 16 + l15) * 64 + ((32 + l4 * 8) ^ flip)];
    if (kt + 1 < nk) STG(As[c ^ 1][1], Ab[1], kt + 1);
    __builtin_amdgcn_s_barrier();
    asm volatile("s_waitcnt lgkmcnt(0)" ::: "memory");
    __builtin_amdgcn_s_setprio(1);
#pragma unroll
    for (int mr = 0; mr < 4; ++mr)
#pragma unroll
      for (int nr = 0; nr < 4; ++nr)
        acc[mr][nr] = __builtin_amdgcn_mfma_f32_16x16x32_bf16(af[mr], bfr[nr], acc[mr][nr], 0, 0, 0);
    __builtin_amdgcn_s_setprio(0);
    __builtin_amdgcn_s_barrier();
    // ---- P4: kh1, m4-7 x n0-3 ----
#pragma unroll
    for (int mr = 0; mr < 4; ++mr)
      af[mr] = *(const bf16x8*)&As[c][wm][((4 + mr) * 16 + l15) * 64 + ((32 + l4 * 8) ^ flip)];
    if (kt + 2 < nk) STG(Bs[c][0], Bb[0], kt + 2);
    __builtin_amdgcn_s_barrier();
    asm volatile("s_waitcnt lgkmcnt(0)" ::: "memory");
    __builtin_amdgcn_s_setprio(1);
#pragma unroll
    for (int mr = 0; mr < 4; ++mr)
#pragma unroll
      for (int nr = 0; nr < 4; ++nr)
        acc[4 + mr][nr] = __builtin_amdgcn_mfma_f32_16x16x32_bf16(af[mr], bfr[nr], acc[4 + mr][nr], 0, 0, 0);
    __builtin_amdgcn_s_setprio(0);
    if (kt < nk - 2) asm volatile("s_waitcnt vmcnt(2)" ::: "memory");
    else             asm volatile("s_waitcnt vmcnt(0)" ::: "memory");
    __builtin_amdgcn_s_barrier();
  }
#undef STG
  // epilogue
#pragma unroll
  for (int mr = 0; mr < 8; ++mr)
#pragma unroll
    for (int nr = 0; nr < 4; ++nr) {
      int col = n0 + wn * 64 + nr * 16 + l15;
      float bv = bias[col];
#pragma unroll
      for (int j = 0; j < 4; ++j) {
        int row = m0 + wm * 128 + mr * 16 + l4 * 4 + j;
        float val = acc[mr][nr][j] + bv;
        if (OUTF32) ((float*)outp)[(size_t)row * N + col] = val;
        else        ((u16*)outp)[(size_t)row * N + col] = f2bf(val);
      }
    }
}

// -------- fused attention (exact R3 anchor) --------
__global__ __launch_bounds__(512, 4) void attn_fused(const u16* __restrict__ qkv, const float* __restrict__ mask,
                                                     float* __restrict__ scores, u16* __restrict__ attnout) {
  __shared__ u16 Ks[2][64 * 64];
  __shared__ u16 Vt[2][64 * 68];
  __shared__ u16 Ps[8][16][72];
  __shared__ float MB[S_LEN];
  const int bid = blockIdx.x;
  const int qt = bid & 15, h = (bid >> 4) & 15, b = bid >> 8;
  const int t = threadIdx.x, lane = t & 63, w = t >> 6;
  const int l15 = lane & 15, l4 = lane >> 4;
  const u16* kbase = qkv + (size_t)b * S_LEN * NQKV + D_MODEL + h * DK;
  const u16* vbase = kbase + D_MODEL;

  {
    float4 m4 = *(const float4*)&mask[b * S_LEN + t * 4];
    MB[t * 4 + 0] = -10000.0f * (1.0f - m4.x);
    MB[t * 4 + 1] = -10000.0f * (1.0f - m4.y);
    MB[t * 4 + 2] = -10000.0f * (1.0f - m4.z);
    MB[t * 4 + 3] = -10000.0f * (1.0f - m4.w);
  }

  bf16x8 qf[2];
  {
    const int qrow = qt * 128 + w * 16 + l15;
    const u16* qp = qkv + (size_t)(b * S_LEN + qrow) * NQKV + h * DK;
#pragma unroll
    for (int ks = 0; ks < 2; ++ks) {
      union { bf16x8 v; u16 s[8]; } qa;
      qa.v = *(const bf16x8*)&qp[ks * 32 + l4 * 8];
#pragma unroll
      for (int e = 0; e < 8; ++e) qa.s[e] = f2bf(bf2f(qa.s[e]) * 0.125f);
      qf[ks] = qa.v;
    }
  }

  const int krow = w * 8 + (lane >> 3);
  const int kchunk = ((lane & 7) ^ (krow & 7)) * 8;
#define STAGE_K(buf, kt) \
  gload16(&kbase[(size_t)((kt) * 64 + krow) * NQKV + kchunk], &Ks[buf][w * 512])

  float ps4[4] = {0.f, 0.f, 0.f, 0.f};
  int cur = 0;
  STAGE_K(0, 0);
  __syncthreads();
  for (int kt = 0; kt < 32; ++kt) {
    if (kt + 1 < 32) STAGE_K(cur ^ 1, kt + 1);
    f32x4 sacc[4] = {};
#pragma unroll
    for (int ks = 0; ks < 2; ++ks) {
      bf16x8 kf[4];
#pragma unroll
      for (int n = 0; n < 4; ++n) {
        int kr = n * 16 + l15;
        kf[n] = *(const bf16x8*)&Ks[cur][kr * 64 + ((ks * 4 + l4) ^ (kr & 7)) * 8];
      }
#pragma unroll
      for (int n = 0; n < 4; ++n)
        sacc[n] = __builtin_amdgcn_mfma_f32_16x16x32_bf16(qf[ks], kf[n], sacc[n], 0, 0, 0);
    }
#pragma unroll
    for (int n = 0; n < 4; ++n) {
      float mb = MB[kt * 64 + n * 16 + l15];
#pragma unroll
      for (int j = 0; j < 4; ++j) ps4[j] += __expf(sacc[n][j] + mb);
    }
    __syncthreads();
    cur ^= 1;
  }
#pragma unroll
  for (int off = 1; off < 16; off <<= 1)
#pragma unroll
    for (int j = 0; j < 4; ++j) ps4[j] += __shfl_xor(ps4[j], off, 64);
  float inv4[4];
#pragma unroll
  for (int j = 0; j < 4; ++j) inv4[j] = 1.0f / ps4[j];

  f32x4 oacc[4] = {};
  const int vr = t >> 3, vc = (t & 7) * 8;
  const size_t sbase = ((size_t)((b * NH + h) * S_LEN + qt * 128 + w * 16 + l4 * 4)) * S_LEN + l15;

  STAGE_K(0, 0);
  {
    const u16* vp = &vbase[(size_t)vr * NQKV + vc];
    int4 va0 = *(const int4*)vp;
    const u16* s0 = (const u16*)&va0;
#pragma unroll
    for (int i = 0; i < 8; ++i) Vt[0][(vc + i) * 68 + vr] = s0[i];
  }
  __syncthreads();
  cur = 0;
  for (int kt = 0; kt < 32; ++kt) {
    const bool hn = (kt + 1 < 32);
    int4 va;
    if (hn) {
      STAGE_K(cur ^ 1, kt + 1);
      va = *(const int4*)&vbase[(size_t)((kt + 1) * 64 + vr) * NQKV + vc];
    }
    f32x4 sacc[4] = {};
#pragma unroll
    for (int ks = 0; ks < 2; ++ks) {
      bf16x8 kf[4];
#pragma unroll
      for (int n = 0; n < 4; ++n) {
        int kr = n * 16 + l15;
        kf[n] = *(const bf16x8*)&Ks[cur][kr * 64 + ((ks * 4 + l4) ^ (kr & 7)) * 8];
      }
#pragma unroll
      for (int n = 0; n < 4; ++n)
        sacc[n] = __builtin_amdgcn_mfma_f32_16x16x32_bf16(qf[ks], kf[n], sacc[n], 0, 0, 0);
    }
#pragma unroll
    for (int n = 0; n < 4; ++n) {
      float mb = MB[kt * 64 + n * 16 + l15];
#pragma unroll
      for (int j = 0; j < 4; ++j) {
        float p = __expf(sacc[n][j] + mb) * inv4[j];
        scores[sbase + (size_t)j * S_LEN + kt * 64 + n * 16] = p;
        Ps[w][l4 * 4 + j][n * 16 + l15] = f2bf(p);
      }
    }
#pragma unroll
    for (int ks = 0; ks < 2; ++ks) {
      bf16x8 pa = *(const bf16x8*)&Ps[w][l15][ks * 32 + l4 * 8];
      bf16x8 vf[4];
#pragma unroll
      for (int dn = 0; dn < 4; ++dn)
        vf[dn] = *(const bf16x8*)&Vt[cur][(dn * 16 + l15) * 68 + ks * 32 + l4 * 8];
#pragma unroll
      for (int dn = 0; dn < 4; ++dn)
        oacc[dn] = __builtin_amdgcn_mfma_f32_16x16x32_bf16(pa, vf[dn], oacc[dn], 0, 0, 0);
    }
    if (hn) {
      const u16* s0 = (const u16*)&va;
#pragma unroll
      for (int i = 0; i < 8; ++i) Vt[cur ^ 1][(vc + i) * 68 + vr] = s0[i];
    }
    __syncthreads();
    cur ^= 1;
  }
#undef STAGE_K
#pragma unroll
  for (int dn = 0; dn < 4; ++dn) {
    int row = b * S_LEN + qt * 128 + w * 16 + l4 * 4;
    int col = h * DK + dn * 16 + l15;
#pragma unroll
    for (int j = 0; j < 4; ++j)
      attnout[(size_t)(row + j) * D_MODEL + col] = f2bf(oacc[dn][j]);
  }
}

extern "C" void kernel_launch(void* const* d_in, const int* in_sizes, int n_in,
                              void* d_out, int out_size, void* d_ws, size_t ws_size,
                              hipStream_t stream) {
  const float* x      = (const float*)d_in[0];
  const float* mask   = (const float*)d_in[1];
  const float* W_attn = (const float*)d_in[2];
  const float* b_attn = (const float*)d_in[3];
  const float* W_proj = (const float*)d_in[4];
  const float* b_proj = (const float*)d_in[5];
  float* out    = (float*)d_out;
  float* scores = out + (size_t)M_ROWS * D_MODEL;

  char* ws = (char*)d_ws;
  u16* xb     = (u16*)ws;                          // 8 MB  : x bf16 [4096,1024]
  u16* wqkvT  = (u16*)(ws + (size_t)(8  << 20));   // 6 MB  : W_attn^T bf16 [3072,1024]
  u16* wprojT = (u16*)(ws + (size_t)(14 << 20));   // 2 MB  : W_proj^T bf16 [1024,1024]
  u16* qkv    = (u16*)(ws + (size_t)(16 << 20));   // 24 MB : qkv bf16 [4096,3072]
  u16* attnb  = (u16*)(ws + (size_t)(40 << 20));   // 8 MB  : attn out bf16 [4096,1024]

  pack_bf16<<<(M_ROWS * D_MODEL) / (256 * 8), 256, 0, stream>>>(x, xb);
  transpose_pack<<<dim3(D_MODEL / 64, NQKV / 64), 256, 0, stream>>>(W_attn, wqkvT, D_MODEL, NQKV);
  transpose_pack<<<dim3(D_MODEL / 64, D_MODEL / 64), 256, 0, stream>>>(W_proj, wprojT, D_MODEL, D_MODEL);
  gemm8p<0><<<dim3(M_ROWS / 256, NQKV / 256), 512, 0, stream>>>(xb, wqkvT, b_attn, (void*)qkv, D_MODEL, NQKV);
  attn_fused<<<BATCH * NH * (S_LEN / 128), 512, 0, stream>>>(qkv, mask, scores, attnb);
  gemm_bt<1><<<dim3(M_ROWS / 128, D_MODEL / 128), 256, 0, stream>>>(attnb, wprojT, b_proj, (void*)out, D_MODEL, D_MODEL);
}